// Round 15
// baseline (1115.306 us; speedup 1.0000x reference)
//
#include <hip/hip_runtime.h>
#include <math.h>
#include <stdint.h>

#define B_ 64
#define N_ 4096
#define K_ 64
#define D_ 256
#define NS_ 8
#define XPAD 264

// wave-private LDS sync: HW DS ops are in-order per wave; the waitcnt gives
// write->read visibility, the "memory" clobber stops compiler reordering.
#define FENCE_LGKM() asm volatile("s_waitcnt lgkmcnt(0)" ::: "memory")
// WAR-only ordering (HW in-order per wave): compiler barrier suffices.
#define CBAR() asm volatile("" ::: "memory")

// ================= bitwise-IEEE helpers (no contraction) =================
__device__ __forceinline__ float fadd(float a, float b) { return __fadd_rn(a, b); }
__device__ __forceinline__ float fmul(float a, float b) { return __fmul_rn(a, b); }

// numpy f32 SIMD exp (loops_exponent_log.dispatch, FMA/AVX512 targets)
__device__ __forceinline__ float np_expf(float x) {
  const float LOG2E = 1.442695040888963407359924681001892137f;
  float qf = rintf(__fmul_rn(x, LOG2E));
  float r = __fmaf_rn(qf, -6.93145752e-1f, x);   // NPY_CODY_WAITE_LOGE_2_HIGHf
  r = __fmaf_rn(qf, -1.42860677e-6f, r);         // NPY_CODY_WAITE_LOGE_2_LOWf
  float num = __fmaf_rn(r, 5.082762527590693718096e-04f, 6.757896990527504603057e-03f);
  num = __fmaf_rn(num, r, 5.114512081637298353406e-02f);
  num = __fmaf_rn(num, r, 2.473615434895520810817e-01f);
  num = __fmaf_rn(num, r, 7.257664613233124478488e-01f);
  num = __fmaf_rn(num, r, 9.999999999980870924916e-01f);
  float den = __fmaf_rn(r, 2.159509375685829852307e-02f, -2.742335390411667452936e-01f);
  den = __fmaf_rn(den, r, 1.000000000000000000000e+00f);
  float poly = __fdiv_rn(num, den);
  int qi = (int)qf;
  float scale = __int_as_float((127 + qi) << 23);
  return __fmul_rn(poly, scale);
}

// ================= JAX threefry2x32 (key=(0,42)), partitionable =================
__device__ __forceinline__ uint32_t rotl32(uint32_t x, int r) {
  return (x << r) | (x >> (32 - r));
}
__device__ __forceinline__ float jax_normal_from_index(uint32_t i) {
  uint32_t x0 = 0u, x1 = i;
  const uint32_t ks0 = 0u, ks1 = 42u, ks2 = 0x1BD11BDAu ^ 0u ^ 42u;
  x0 += ks0; x1 += ks1;
#define TF_ROUND(r) { x0 += x1; x1 = rotl32(x1, (r)); x1 ^= x0; }
  TF_ROUND(13) TF_ROUND(15) TF_ROUND(26) TF_ROUND(6)
  x0 += ks1; x1 += ks2 + 1u;
  TF_ROUND(17) TF_ROUND(29) TF_ROUND(16) TF_ROUND(24)
  x0 += ks2; x1 += ks0 + 2u;
  TF_ROUND(13) TF_ROUND(15) TF_ROUND(26) TF_ROUND(6)
  x0 += ks0; x1 += ks1 + 3u;
  TF_ROUND(17) TF_ROUND(29) TF_ROUND(16) TF_ROUND(24)
  x0 += ks1; x1 += ks2 + 4u;
  TF_ROUND(13) TF_ROUND(15) TF_ROUND(26) TF_ROUND(6)
  x0 += ks2; x1 += ks0 + 5u;
#undef TF_ROUND
  uint32_t bits = x0 ^ x1;
  uint32_t fb = (bits >> 9) | 0x3f800000u;
  float f = __uint_as_float(fb) - 1.0f;
  const float lo = __uint_as_float(0xBF7FFFFFu);
  float u = f * 2.0f + lo;
  u = fmaxf(lo, u);
  float w = -log1pf(-u * u);
  float p;
  if (w < 5.0f) {
    w = w - 2.5f;
    p = 2.81022636e-08f;
    p = fmaf(p, w, 3.43273939e-07f);
    p = fmaf(p, w, -3.5233877e-06f);
    p = fmaf(p, w, -4.39150654e-06f);
    p = fmaf(p, w, 0.00021858087f);
    p = fmaf(p, w, -0.00125372503f);
    p = fmaf(p, w, -0.00417768164f);
    p = fmaf(p, w, 0.246640727f);
    p = fmaf(p, w, 1.50140941f);
  } else {
    w = sqrtf(w) - 3.0f;
    p = -0.000200214257f;
    p = fmaf(p, w, 0.000100950558f);
    p = fmaf(p, w, 0.00134934322f);
    p = fmaf(p, w, -0.00367342844f);
    p = fmaf(p, w, 0.00573950773f);
    p = fmaf(p, w, -0.0076224613f);
    p = fmaf(p, w, 0.00943887047f);
    p = fmaf(p, w, 1.00167406f);
    p = fmaf(p, w, 2.83297682f);
  }
  return 1.41421356f * (p * u);
}

// numpy pairwise-128 of squares (AVX512)
__device__ __forceinline__ float np_pw128_sq(const float* p) {
  float t16[16];
#pragma unroll
  for (int L = 0; L < 16; ++L) {
    float q0 = p[L];       q0 = fmul(q0, q0);
    float q1 = p[L + 16];  q1 = fmul(q1, q1);
    float q2 = p[L + 32];  q2 = fmul(q2, q2);
    float q3 = p[L + 48];  q3 = fmul(q3, q3);
    float q4 = p[L + 64];  q4 = fmul(q4, q4);
    float q5 = p[L + 80];  q5 = fmul(q5, q5);
    float q6 = p[L + 96];  q6 = fmul(q6, q6);
    float q7 = p[L + 112]; q7 = fmul(q7, q7);
    t16[L] = fadd(fadd(fadd(q0, q4), fadd(q1, q5)), fadd(fadd(q2, q6), fadd(q3, q7)));
  }
  float u8[8];
#pragma unroll
  for (int L = 0; L < 8; ++L) u8[L] = fadd(t16[L], t16[L + 8]);
  float v4[4];
#pragma unroll
  for (int L = 0; L < 4; ++L) v4[L] = fadd(u8[L], u8[L + 4]);
  return fadd(fadd(v4[0], v4[2]), fadd(v4[1], v4[3]));
}

// numpy sum of 64 contiguous f32 (AVX512, n=64 one block)
__device__ __forceinline__ float np_sum64(const float* a) {
  float t16[16];
#pragma unroll
  for (int L = 0; L < 16; ++L)
    t16[L] = fadd(fadd(a[L], a[16 + L]), fadd(a[32 + L], a[48 + L]));
  float u8[8];
#pragma unroll
  for (int L = 0; L < 8; ++L) u8[L] = fadd(t16[L], t16[L + 8]);
  float v4[4];
#pragma unroll
  for (int L = 0; L < 4; ++L) v4[L] = fadd(u8[L], u8[L + 4]);
  return fadd(fadd(v4[0], v4[2]), fadd(v4[1], v4[3]));
}

// ============ prep: mn = mu / max(np_norm(mu_row), 1e-8), stored transposed ============
__global__ __launch_bounds__(64)
void prep_mnT(const float* __restrict__ mu, float4* __restrict__ mnT4) {
  const int k = threadIdx.x;
  const float* mrow = mu + k * D_;
  const float n2 = fadd(np_pw128_sq(mrow), np_pw128_sq(mrow + 128));
  const float den = fmaxf(__fsqrt_rn(n2), 1e-8f);
#pragma unroll 8
  for (int t = 0; t < 64; ++t) {
    float4 m = *(const float4*)&mrow[4 * t];
    float4 o;
    o.x = __fdiv_rn(m.x, den); o.y = __fdiv_rn(m.y, den);
    o.z = __fdiv_rn(m.z, den); o.w = __fdiv_rn(m.w, den);
    mnT4[t * K_ + k] = o;   // mnT4[t][k] = mn[k][4t..4t+3]
  }
}

// ================= shared phase: numpy AVX512 norm of a staged row set =================
// (16-lane trees; numpy value at L16==0). Used by both tiers.
__device__ __forceinline__ void np_norm4(const float* rowp, int L16, float* den_out) {
  float res2[2];
#pragma unroll
  for (int half = 0; half < 2; ++half) {
    const float* p = rowp + half * 128 + L16;
    float q0 = p[0];   q0 = fmul(q0, q0);
    float q1 = p[16];  q1 = fmul(q1, q1);
    float q2 = p[32];  q2 = fmul(q2, q2);
    float q3 = p[48];  q3 = fmul(q3, q3);
    float q4 = p[64];  q4 = fmul(q4, q4);
    float q5 = p[80];  q5 = fmul(q5, q5);
    float q6 = p[96];  q6 = fmul(q6, q6);
    float q7 = p[112]; q7 = fmul(q7, q7);
    const float t = fadd(fadd(fadd(q0, q4), fadd(q1, q5)),
                         fadd(fadd(q2, q6), fadd(q3, q7)));
    float u  = fadd(t, __shfl_xor(t, 8));
    float v  = fadd(u, __shfl_xor(u, 4));
    float w2 = fadd(v, __shfl_xor(v, 2));
    res2[half] = fadd(w2, __shfl_xor(w2, 1));
  }
  const float n2 = fadd(res2[0], res2[1]);
  *den_out = fmaxf(__fsqrt_rn(n2), 1e-8f);
}

// ================= shared phase: numpy softmax over k=64 (lane = k) =================
__device__ __forceinline__ float np_softmax64(float cosr) {
  float mx = cosr;
  mx = fmaxf(mx, __shfl_xor(mx, 1));
  mx = fmaxf(mx, __shfl_xor(mx, 2));
  mx = fmaxf(mx, __shfl_xor(mx, 4));
  mx = fmaxf(mx, __shfl_xor(mx, 8));
  mx = fmaxf(mx, __shfl_xor(mx, 16));
  mx = fmaxf(mx, __shfl_xor(mx, 32));
  const float e = np_expf(__fsub_rn(cosr, mx));
  float g1 = fadd(e, __shfl_xor(e, 16));
  float g2 = fadd(g1, __shfl_xor(g1, 32));
  float u  = fadd(g2, __shfl_xor(g2, 8));
  float v  = fadd(u, __shfl_xor(u, 4));
  float w2 = fadd(v, __shfl_xor(v, 2));
  float sres = fadd(w2, __shfl_xor(w2, 1));
  const float denom = __shfl(sres, 0);
  return __fdiv_rn(e, denom);
}

// ============ TIER-1 kernel A: xn = x / max(np_norm(x_row), 1e-8) -> global ============
// grid (64 b, 8 seg), block 1024 (16 waves, __launch_bounds__ for 2 blocks/CU).
__global__ __launch_bounds__(1024, 8)
void xn_write(const float* __restrict__ x, float* __restrict__ xn) {
  __shared__ float xst[16][4][XPAD];
  const int b = blockIdx.x;
  const int seg = blockIdx.y;
  const int tid = threadIdx.x;
  const int w = tid >> 6;
  const int lane = tid & 63;
  const int L16 = lane & 15;
  const int rowg = lane >> 4;

  float4 xr[4];
  {
    const int n0 = seg * 512 + w * 4;
#pragma unroll
    for (int r = 0; r < 4; ++r)
      xr[r] = *(const float4*)&x[(((size_t)b << 12) + n0 + r) * D_ + lane * 4];
  }

  for (int pass = 0; pass < 8; ++pass) {
    const int n0 = seg * 512 + pass * 64 + w * 4;
#pragma unroll
    for (int r = 0; r < 4; ++r)
      *(float4*)&xst[w][r][lane * 4] = xr[r];
    FENCE_LGKM();   // RAW: stage writes -> cross-lane norm reads

    if (pass < 7) {
      const int n1 = n0 + 64;
#pragma unroll
      for (int r = 0; r < 4; ++r)
        xr[r] = *(const float4*)&x[(((size_t)b << 12) + n1 + r) * D_ + lane * 4];
    }

    float den4[4];
    {
      float den;
      np_norm4(&xst[w][rowg][0], L16, &den);   // valid at lanes 0,16,32,48
#pragma unroll
      for (int r = 0; r < 4; ++r) den4[r] = __shfl(den, 16 * r);
    }

    // divide staged values, write xn to global (coalesced)
#pragma unroll
    for (int r = 0; r < 4; ++r) {
      const float4 v = *(const float4*)&xst[w][r][lane * 4];
      float4 o;
      o.x = __fdiv_rn(v.x, den4[r]); o.y = __fdiv_rn(v.y, den4[r]);
      o.z = __fdiv_rn(v.z, den4[r]); o.w = __fdiv_rn(v.w, den4[r]);
      *(float4*)&xn[(((size_t)b << 12) + n0 + r) * D_ + lane * 4] = o;
    }
    CBAR();   // WAR: xst reads ordered before next pass's stage writes
  }
}

// ============ TIER-1 kernel B: cos (VMEM xn + LDS mn) -> softmax -> p ============
// grid (64 b, 16 seg), block 512 (8 waves), LDS 64 KB -> 2 blocks/CU.
// Wave w: 8 rows/pass, 4 passes. No LDS writes after init -> no fences.
__global__ __launch_bounds__(512, 4)
void cos_softmax_xn(const float* __restrict__ xn,
                    const float4* __restrict__ mnT4_g,
                    float* __restrict__ p_ws) {
  __shared__ float4 mnT4[64][64];   // [t][k]  64 KiB
  const int b = blockIdx.x;
  const int seg = blockIdx.y;
  const int tid = threadIdx.x;
  const int w = tid >> 6;
  const int lane = tid & 63;

#pragma unroll
  for (int i = 0; i < 8; ++i)
    ((float4*)mnT4)[tid * 8 + i] = mnT4_g[tid * 8 + i];
  __syncthreads();

  for (int pass = 0; pass < 4; ++pass) {
    const int rowbase = seg * 256 + pass * 64 + w * 8;
    const float* xrow = xn + (((size_t)b << 12) + rowbase) * D_;

    float acc[8][4];
#pragma unroll
    for (int r = 0; r < 8; ++r)
#pragma unroll
      for (int j = 0; j < 4; ++j) acc[r][j] = 0.f;

#pragma unroll 4
    for (int t = 0; t < 64; ++t) {
      const float4 m4 = mnT4[t][lane];
#pragma unroll
      for (int r = 0; r < 8; ++r) {
        const float4 x4 = *(const float4*)&xrow[(size_t)r * D_ + 4 * t];
        acc[r][0] = fadd(acc[r][0], fmul(x4.x, m4.x));
        acc[r][1] = fadd(acc[r][1], fmul(x4.y, m4.y));
        acc[r][2] = fadd(acc[r][2], fmul(x4.z, m4.z));
        acc[r][3] = fadd(acc[r][3], fmul(x4.w, m4.w));
      }
    }

#pragma unroll
    for (int r = 0; r < 8; ++r) {
      // SSE3 hadd horizontal: (l0+l1)+(l2+l3)
      const float cosr = fadd(fadd(acc[r][0], acc[r][1]), fadd(acc[r][2], acc[r][3]));
      const float p = np_softmax64(cosr);
      p_ws[(((size_t)b << 12) + rowbase + r) * K_ + lane] = p;
    }
  }
}

// ============ LEGACY (fallback if ws too small): fused r11/r13 path ============
__global__ __launch_bounds__(1024, 1)
void xn_cos_softmax_legacy(const float* __restrict__ x,
                           const float4* __restrict__ mnT4_g,
                           float* __restrict__ p_ws) {
  __shared__ float4 mnT4[64][64];
  __shared__ float xst[16][4][XPAD];
  const int b = blockIdx.x;
  const int seg = blockIdx.y;
  const int tid = threadIdx.x;
  const int w = tid >> 6;
  const int lane = tid & 63;

#pragma unroll
  for (int i = 0; i < 4; ++i)
    ((float4*)mnT4)[tid * 4 + i] = mnT4_g[tid * 4 + i];
  __syncthreads();

  const int L16 = lane & 15;
  const int rowg = lane >> 4;

  float4 xr[4];
  {
    const int n0 = seg * 512 + w * 4;
#pragma unroll
    for (int r = 0; r < 4; ++r)
      xr[r] = *(const float4*)&x[(((size_t)b << 12) + n0 + r) * D_ + lane * 4];
  }

  for (int pass = 0; pass < 8; ++pass) {
    const int n0 = seg * 512 + pass * 64 + w * 4;
#pragma unroll
    for (int r = 0; r < 4; ++r)
      *(float4*)&xst[w][r][lane * 4] = xr[r];
    FENCE_LGKM();

    if (pass < 7) {
      const int n1 = n0 + 64;
#pragma unroll
      for (int r = 0; r < 4; ++r)
        xr[r] = *(const float4*)&x[(((size_t)b << 12) + n1 + r) * D_ + lane * 4];
    }

    float den4[4];
    {
      float den;
      np_norm4(&xst[w][rowg][0], L16, &den);
#pragma unroll
      for (int r = 0; r < 4; ++r) den4[r] = __shfl(den, 16 * r);
    }
    CBAR();

#pragma unroll
    for (int r = 0; r < 4; ++r) {
      float4 v = *(float4*)&xst[w][r][lane * 4];
      v.x = __fdiv_rn(v.x, den4[r]); v.y = __fdiv_rn(v.y, den4[r]);
      v.z = __fdiv_rn(v.z, den4[r]); v.w = __fdiv_rn(v.w, den4[r]);
      *(float4*)&xst[w][r][lane * 4] = v;
    }
    FENCE_LGKM();

    float acc[4][4];
#pragma unroll
    for (int r = 0; r < 4; ++r)
#pragma unroll
      for (int j = 0; j < 4; ++j) acc[r][j] = 0.f;

#pragma unroll 4
    for (int t = 0; t < 64; ++t) {
      const float4 m4 = mnT4[t][lane];
#pragma unroll
      for (int r = 0; r < 4; ++r) {
        const float4 x4 = *(const float4*)&xst[w][r][4 * t];
        acc[r][0] = fadd(acc[r][0], fmul(x4.x, m4.x));
        acc[r][1] = fadd(acc[r][1], fmul(x4.y, m4.y));
        acc[r][2] = fadd(acc[r][2], fmul(x4.z, m4.z));
        acc[r][3] = fadd(acc[r][3], fmul(x4.w, m4.w));
      }
    }

#pragma unroll
    for (int r = 0; r < 4; ++r) {
      const float cosr = fadd(fadd(acc[r][0], acc[r][1]), fadd(acc[r][2], acc[r][3]));
      const float p = np_softmax64(cosr);
      p_ws[(((size_t)b << 12) + n0 + r) * K_ + lane] = p;
    }
    CBAR();
  }
}

// ============ stage 2: numpy PAIRWISE f32 sum over n=4096 (leaf groups) ============
__global__ __launch_bounds__(256)
void pairwise_sum_n(const float* __restrict__ p_ws, float* __restrict__ s_part) {
  __shared__ float part[4][K_];
  const int b = blockIdx.x;
  const int g = blockIdx.y;
  const int w = threadIdx.x >> 6;
  const int k = threadIdx.x & 63;
  const float* base = p_ws + ((size_t)b << 12) * K_ + k;

  float l[2];
#pragma unroll 1
  for (int i = 0; i < 2; ++i) {
    const float* leaf = base + (size_t)(g * 8 + w * 2 + i) * 128 * K_;
    float c[16];
#pragma unroll
    for (int L = 0; L < 16; ++L) {
      const float* pL = leaf + (size_t)L * K_;
      const float q0 = pL[0 * 16 * K_];
      const float q1 = pL[1 * 16 * K_];
      const float q2 = pL[2 * 16 * K_];
      const float q3 = pL[3 * 16 * K_];
      const float q4 = pL[4 * 16 * K_];
      const float q5 = pL[5 * 16 * K_];
      const float q6 = pL[6 * 16 * K_];
      const float q7 = pL[7 * 16 * K_];
      c[L] = fadd(fadd(fadd(q0, q4), fadd(q1, q5)), fadd(fadd(q2, q6), fadd(q3, q7)));
    }
    float u8[8];
#pragma unroll
    for (int L = 0; L < 8; ++L) u8[L] = fadd(c[L], c[L + 8]);
    float v4[4];
#pragma unroll
    for (int L = 0; L < 4; ++L) v4[L] = fadd(u8[L], u8[L + 4]);
    l[i] = fadd(fadd(v4[0], v4[2]), fadd(v4[1], v4[3]));
  }
  part[w][k] = fadd(l[0], l[1]);
  __syncthreads();
  if (w == 0) {
    const float Sg = fadd(fadd(part[0][k], part[1][k]), fadd(part[2][k], part[3][k]));
    s_part[(b * 4 + g) * K_ + k] = Sg;
  }
}

// ============ root combine + bitwise final softmax -> top-8 -> sample ============
__global__ __launch_bounds__(256)
void topk_sample(const float* __restrict__ s_part,
                 const float* __restrict__ mu,
                 const float* __restrict__ ls,
                 float* __restrict__ out) {
  __shared__ float sv[K_];
  __shared__ int sidx[NS_];
  const int b = blockIdx.x;
  const int t = threadIdx.x;
  if (t < K_) {
    const float S0 = s_part[(b * 4 + 0) * K_ + t];
    const float S1 = s_part[(b * 4 + 1) * K_ + t];
    const float S2 = s_part[(b * 4 + 2) * K_ + t];
    const float S3 = s_part[(b * 4 + 3) * K_ + t];
    sv[t] = fadd(fadd(S0, S1), fadd(S2, S3));
  }
  __syncthreads();
  if (t == 0) {
    float mx = sv[0];
    for (int k = 1; k < K_; ++k) mx = fmaxf(mx, sv[k]);
    float e[K_];
    for (int k = 0; k < K_; ++k) e[k] = np_expf(__fsub_rn(sv[k], mx));
    const float denom = np_sum64(e);
    float rv[K_];
    for (int k = 0; k < K_; ++k) rv[k] = __fdiv_rn(e[k], denom);
    for (int q = 0; q < NS_; ++q) {
      float best = -1.0e30f; int bi = 0;
      for (int k = 0; k < K_; ++k) {
        if (rv[k] > best) { best = rv[k]; bi = k; }
      }
      sidx[q] = bi;
      rv[bi] = -1.0e30f;
    }
  }
  __syncthreads();

  const int q = t >> 5;
  const int d0 = (t & 31) * 8;
  const int k = sidx[q];
  const float* mrow = mu + k * D_ + d0;
  const float* lrow = ls + k * D_ + d0;
  float* orow = out + ((size_t)b * NS_ + q) * D_ + d0;
  const uint32_t ibase = (uint32_t)(((b * NS_) + q) * D_ + d0);
#pragma unroll
  for (int j = 0; j < 8; ++j) {
    const float z = jax_normal_from_index(ibase + (uint32_t)j);
    orow[j] = fmaf(expf(lrow[j]), z, mrow[j]);
  }
}

extern "C" void kernel_launch(void* const* d_in, const int* in_sizes, int n_in,
                              void* d_out, int out_size, void* d_ws, size_t ws_size,
                              hipStream_t stream) {
  const float* x  = (const float*)d_in[0];
  const float* mu = (const float*)d_in[1];
  const float* ls = (const float*)d_in[2];
  float* out = (float*)d_out;
  (void)in_sizes; (void)n_in; (void)out_size;

  const size_t XN_BYTES = (size_t)B_ * N_ * D_ * 4;   // 256 MiB
  const size_t P_BYTES  = (size_t)B_ * N_ * K_ * 4;   // 64 MiB
  const size_t NEED_T1  = XN_BYTES + P_BYTES + 65536 + 65536;

  if (ws_size >= NEED_T1) {
    // Tier-1: split path (xn precompute -> VMEM/LDS-split dot)
    float*  xn     = (float*)d_ws;
    float*  p_ws   = (float*)((char*)d_ws + XN_BYTES);
    float*  s_part = (float*)((char*)d_ws + XN_BYTES + P_BYTES);
    float4* mnT4   = (float4*)((char*)d_ws + XN_BYTES + P_BYTES + 65536);

    prep_mnT<<<1, 64, 0, stream>>>(mu, mnT4);
    dim3 gridA(B_, 8);
    xn_write<<<gridA, 1024, 0, stream>>>(x, xn);
    dim3 gridB(B_, 16);
    cos_softmax_xn<<<gridB, 512, 0, stream>>>(xn, mnT4, p_ws);
    dim3 grid2(B_, 4);
    pairwise_sum_n<<<grid2, 256, 0, stream>>>(p_ws, s_part);
    topk_sample<<<B_, 256, 0, stream>>>(s_part, mu, ls, out);
  } else {
    // Fallback: legacy fused path (67.2 MiB workspace)
    float*  p_ws   = (float*)d_ws;
    float*  s_part = (float*)((char*)d_ws + P_BYTES);
    float4* mnT4   = (float4*)((char*)d_ws + P_BYTES + 65536);

    prep_mnT<<<1, 64, 0, stream>>>(mu, mnT4);
    dim3 grid(B_, 8);
    xn_cos_softmax_legacy<<<grid, 1024, 0, stream>>>(x, mnT4, p_ws);
    dim3 grid2(B_, 4);
    pairwise_sum_n<<<grid2, 256, 0, stream>>>(p_ws, s_part);
    topk_sample<<<B_, 256, 0, stream>>>(s_part, mu, ls, out);
  }
}

// Round 16
// 631.565 us; speedup vs baseline: 1.7659x; 1.7659x over previous
//
#include <hip/hip_runtime.h>
#include <math.h>
#include <stdint.h>

#define B_ 64
#define N_ 4096
#define K_ 64
#define D_ 256
#define NS_ 8
#define XPAD 264

// wave-private LDS sync: HW DS ops are in-order per wave; the waitcnt gives
// write->read visibility, the "memory" clobber stops compiler reordering.
#define FENCE_LGKM() asm volatile("s_waitcnt lgkmcnt(0)" ::: "memory")
// WAR-only ordering (HW in-order per wave): compiler barrier suffices.
#define CBAR() asm volatile("" ::: "memory")

// ================= bitwise-IEEE helpers (no contraction) =================
__device__ __forceinline__ float fadd(float a, float b) { return __fadd_rn(a, b); }
__device__ __forceinline__ float fmul(float a, float b) { return __fmul_rn(a, b); }

// numpy f32 SIMD exp (loops_exponent_log.dispatch, FMA/AVX512 targets)
__device__ __forceinline__ float np_expf(float x) {
  const float LOG2E = 1.442695040888963407359924681001892137f;
  float qf = rintf(__fmul_rn(x, LOG2E));
  float r = __fmaf_rn(qf, -6.93145752e-1f, x);   // NPY_CODY_WAITE_LOGE_2_HIGHf
  r = __fmaf_rn(qf, -1.42860677e-6f, r);         // NPY_CODY_WAITE_LOGE_2_LOWf
  float num = __fmaf_rn(r, 5.082762527590693718096e-04f, 6.757896990527504603057e-03f);
  num = __fmaf_rn(num, r, 5.114512081637298353406e-02f);
  num = __fmaf_rn(num, r, 2.473615434895520810817e-01f);
  num = __fmaf_rn(num, r, 7.257664613233124478488e-01f);
  num = __fmaf_rn(num, r, 9.999999999980870924916e-01f);
  float den = __fmaf_rn(r, 2.159509375685829852307e-02f, -2.742335390411667452936e-01f);
  den = __fmaf_rn(den, r, 1.000000000000000000000e+00f);
  float poly = __fdiv_rn(num, den);
  int qi = (int)qf;
  float scale = __int_as_float((127 + qi) << 23);
  return __fmul_rn(poly, scale);
}

// ================= JAX threefry2x32 (key=(0,42)), partitionable =================
__device__ __forceinline__ uint32_t rotl32(uint32_t x, int r) {
  return (x << r) | (x >> (32 - r));
}
__device__ __forceinline__ float jax_normal_from_index(uint32_t i) {
  uint32_t x0 = 0u, x1 = i;
  const uint32_t ks0 = 0u, ks1 = 42u, ks2 = 0x1BD11BDAu ^ 0u ^ 42u;
  x0 += ks0; x1 += ks1;
#define TF_ROUND(r) { x0 += x1; x1 = rotl32(x1, (r)); x1 ^= x0; }
  TF_ROUND(13) TF_ROUND(15) TF_ROUND(26) TF_ROUND(6)
  x0 += ks1; x1 += ks2 + 1u;
  TF_ROUND(17) TF_ROUND(29) TF_ROUND(16) TF_ROUND(24)
  x0 += ks2; x1 += ks0 + 2u;
  TF_ROUND(13) TF_ROUND(15) TF_ROUND(26) TF_ROUND(6)
  x0 += ks0; x1 += ks1 + 3u;
  TF_ROUND(17) TF_ROUND(29) TF_ROUND(16) TF_ROUND(24)
  x0 += ks1; x1 += ks2 + 4u;
  TF_ROUND(13) TF_ROUND(15) TF_ROUND(26) TF_ROUND(6)
  x0 += ks2; x1 += ks0 + 5u;
#undef TF_ROUND
  uint32_t bits = x0 ^ x1;
  uint32_t fb = (bits >> 9) | 0x3f800000u;
  float f = __uint_as_float(fb) - 1.0f;
  const float lo = __uint_as_float(0xBF7FFFFFu);
  float u = f * 2.0f + lo;
  u = fmaxf(lo, u);
  float w = -log1pf(-u * u);
  float p;
  if (w < 5.0f) {
    w = w - 2.5f;
    p = 2.81022636e-08f;
    p = fmaf(p, w, 3.43273939e-07f);
    p = fmaf(p, w, -3.5233877e-06f);
    p = fmaf(p, w, -4.39150654e-06f);
    p = fmaf(p, w, 0.00021858087f);
    p = fmaf(p, w, -0.00125372503f);
    p = fmaf(p, w, -0.00417768164f);
    p = fmaf(p, w, 0.246640727f);
    p = fmaf(p, w, 1.50140941f);
  } else {
    w = sqrtf(w) - 3.0f;
    p = -0.000200214257f;
    p = fmaf(p, w, 0.000100950558f);
    p = fmaf(p, w, 0.00134934322f);
    p = fmaf(p, w, -0.00367342844f);
    p = fmaf(p, w, 0.00573950773f);
    p = fmaf(p, w, -0.0076224613f);
    p = fmaf(p, w, 0.00943887047f);
    p = fmaf(p, w, 1.00167406f);
    p = fmaf(p, w, 2.83297682f);
  }
  return 1.41421356f * (p * u);
}

// numpy pairwise-128 of squares (AVX512)
__device__ __forceinline__ float np_pw128_sq(const float* p) {
  float t16[16];
#pragma unroll
  for (int L = 0; L < 16; ++L) {
    float q0 = p[L];       q0 = fmul(q0, q0);
    float q1 = p[L + 16];  q1 = fmul(q1, q1);
    float q2 = p[L + 32];  q2 = fmul(q2, q2);
    float q3 = p[L + 48];  q3 = fmul(q3, q3);
    float q4 = p[L + 64];  q4 = fmul(q4, q4);
    float q5 = p[L + 80];  q5 = fmul(q5, q5);
    float q6 = p[L + 96];  q6 = fmul(q6, q6);
    float q7 = p[L + 112]; q7 = fmul(q7, q7);
    t16[L] = fadd(fadd(fadd(q0, q4), fadd(q1, q5)), fadd(fadd(q2, q6), fadd(q3, q7)));
  }
  float u8[8];
#pragma unroll
  for (int L = 0; L < 8; ++L) u8[L] = fadd(t16[L], t16[L + 8]);
  float v4[4];
#pragma unroll
  for (int L = 0; L < 4; ++L) v4[L] = fadd(u8[L], u8[L + 4]);
  return fadd(fadd(v4[0], v4[2]), fadd(v4[1], v4[3]));
}

// numpy sum of 64 contiguous f32 (AVX512, n=64 one block)
__device__ __forceinline__ float np_sum64(const float* a) {
  float t16[16];
#pragma unroll
  for (int L = 0; L < 16; ++L)
    t16[L] = fadd(fadd(a[L], a[16 + L]), fadd(a[32 + L], a[48 + L]));
  float u8[8];
#pragma unroll
  for (int L = 0; L < 8; ++L) u8[L] = fadd(t16[L], t16[L + 8]);
  float v4[4];
#pragma unroll
  for (int L = 0; L < 4; ++L) v4[L] = fadd(u8[L], u8[L + 4]);
  return fadd(fadd(v4[0], v4[2]), fadd(v4[1], v4[3]));
}

// ============ prep: mn = mu / max(np_norm(mu_row), 1e-8), stored transposed ============
__global__ __launch_bounds__(64)
void prep_mnT(const float* __restrict__ mu, float4* __restrict__ mnT4) {
  const int k = threadIdx.x;
  const float* mrow = mu + k * D_;
  const float n2 = fadd(np_pw128_sq(mrow), np_pw128_sq(mrow + 128));
  const float den = fmaxf(__fsqrt_rn(n2), 1e-8f);
#pragma unroll 8
  for (int t = 0; t < 64; ++t) {
    float4 m = *(const float4*)&mrow[4 * t];
    float4 o;
    o.x = __fdiv_rn(m.x, den); o.y = __fdiv_rn(m.y, den);
    o.z = __fdiv_rn(m.z, den); o.w = __fdiv_rn(m.w, den);
    mnT4[t * K_ + k] = o;   // mnT4[t][k] = mn[k][4t..4t+3]
  }
}

// ================= shared phase: numpy AVX512 norm of a staged row set =================
__device__ __forceinline__ void np_norm4(const float* rowp, int L16, float* den_out) {
  float res2[2];
#pragma unroll
  for (int half = 0; half < 2; ++half) {
    const float* p = rowp + half * 128 + L16;
    float q0 = p[0];   q0 = fmul(q0, q0);
    float q1 = p[16];  q1 = fmul(q1, q1);
    float q2 = p[32];  q2 = fmul(q2, q2);
    float q3 = p[48];  q3 = fmul(q3, q3);
    float q4 = p[64];  q4 = fmul(q4, q4);
    float q5 = p[80];  q5 = fmul(q5, q5);
    float q6 = p[96];  q6 = fmul(q6, q6);
    float q7 = p[112]; q7 = fmul(q7, q7);
    const float t = fadd(fadd(fadd(q0, q4), fadd(q1, q5)),
                         fadd(fadd(q2, q6), fadd(q3, q7)));
    float u  = fadd(t, __shfl_xor(t, 8));
    float v  = fadd(u, __shfl_xor(u, 4));
    float w2 = fadd(v, __shfl_xor(v, 2));
    res2[half] = fadd(w2, __shfl_xor(w2, 1));
  }
  const float n2 = fadd(res2[0], res2[1]);
  *den_out = fmaxf(__fsqrt_rn(n2), 1e-8f);
}

// ================= shared phase: numpy softmax over k=64 (lane = k) =================
__device__ __forceinline__ float np_softmax64(float cosr) {
  float mx = cosr;
  mx = fmaxf(mx, __shfl_xor(mx, 1));
  mx = fmaxf(mx, __shfl_xor(mx, 2));
  mx = fmaxf(mx, __shfl_xor(mx, 4));
  mx = fmaxf(mx, __shfl_xor(mx, 8));
  mx = fmaxf(mx, __shfl_xor(mx, 16));
  mx = fmaxf(mx, __shfl_xor(mx, 32));
  const float e = np_expf(__fsub_rn(cosr, mx));
  float g1 = fadd(e, __shfl_xor(e, 16));
  float g2 = fadd(g1, __shfl_xor(g1, 32));
  float u  = fadd(g2, __shfl_xor(g2, 8));
  float v  = fadd(u, __shfl_xor(u, 4));
  float w2 = fadd(v, __shfl_xor(v, 2));
  float sres = fadd(w2, __shfl_xor(w2, 1));
  const float denom = __shfl(sres, 0);
  return __fdiv_rn(e, denom);
}

// ============ TIER-1 kernel A: xn = x / max(np_norm(x_row), 1e-8) -> global ============
__global__ __launch_bounds__(1024, 8)
void xn_write(const float* __restrict__ x, float* __restrict__ xn) {
  __shared__ float xst[16][4][XPAD];
  const int b = blockIdx.x;
  const int seg = blockIdx.y;
  const int tid = threadIdx.x;
  const int w = tid >> 6;
  const int lane = tid & 63;
  const int L16 = lane & 15;
  const int rowg = lane >> 4;

  float4 xr[4];
  {
    const int n0 = seg * 512 + w * 4;
#pragma unroll
    for (int r = 0; r < 4; ++r)
      xr[r] = *(const float4*)&x[(((size_t)b << 12) + n0 + r) * D_ + lane * 4];
  }

  for (int pass = 0; pass < 8; ++pass) {
    const int n0 = seg * 512 + pass * 64 + w * 4;
#pragma unroll
    for (int r = 0; r < 4; ++r)
      *(float4*)&xst[w][r][lane * 4] = xr[r];
    FENCE_LGKM();   // RAW: stage writes -> cross-lane norm reads

    if (pass < 7) {
      const int n1 = n0 + 64;
#pragma unroll
      for (int r = 0; r < 4; ++r)
        xr[r] = *(const float4*)&x[(((size_t)b << 12) + n1 + r) * D_ + lane * 4];
    }

    float den4[4];
    {
      float den;
      np_norm4(&xst[w][rowg][0], L16, &den);   // valid at lanes 0,16,32,48
#pragma unroll
      for (int r = 0; r < 4; ++r) den4[r] = __shfl(den, 16 * r);
    }

#pragma unroll
    for (int r = 0; r < 4; ++r) {
      const float4 v = *(const float4*)&xst[w][r][lane * 4];
      float4 o;
      o.x = __fdiv_rn(v.x, den4[r]); o.y = __fdiv_rn(v.y, den4[r]);
      o.z = __fdiv_rn(v.z, den4[r]); o.w = __fdiv_rn(v.w, den4[r]);
      *(float4*)&xn[(((size_t)b << 12) + n0 + r) * D_ + lane * 4] = o;
    }
    CBAR();   // WAR: xst reads ordered before next pass's stage writes
  }
}

// ============ TIER-1 kernel B (fixed): cos (SMEM xn + LDS mn) -> softmax -> p ============
// grid (64 b, 16 seg), block 512 (8 waves), LDS 64 KB -> 2 blocks/CU.
// Wave wu: 32 rows over 8 passes of 4 rows. x-row addresses are wave-uniform
// (readfirstlane) -> scalar s_load path, zero DS/VGPR pressure for x.
// Register budget: acc[4][4]=16 VGPR; unroll 2 -> <=32 uniform-load SGPRs live.
__global__ __launch_bounds__(512, 4)
void cos_softmax_xn(const float* __restrict__ xn,
                    const float4* __restrict__ mnT4_g,
                    float* __restrict__ p_ws) {
  __shared__ float4 mnT4[64][64];   // [t][k]  64 KiB
  const int b = blockIdx.x;
  const int seg = blockIdx.y;
  const int tid = threadIdx.x;
  const int lane = tid & 63;
  const int wu = __builtin_amdgcn_readfirstlane(tid >> 6);   // wave-uniform in SGPR

#pragma unroll
  for (int i = 0; i < 8; ++i)
    ((float4*)mnT4)[tid * 8 + i] = mnT4_g[tid * 8 + i];
  __syncthreads();

#pragma unroll 1
  for (int pass = 0; pass < 8; ++pass) {
    const int rowbase = seg * 256 + wu * 32 + pass * 4;
    const float* xrow = xn + (((size_t)b << 12) + rowbase) * D_;

    float acc[4][4];
#pragma unroll
    for (int r = 0; r < 4; ++r)
#pragma unroll
      for (int j = 0; j < 4; ++j) acc[r][j] = 0.f;

#pragma unroll 2
    for (int t = 0; t < 64; ++t) {
      const float4 m4 = mnT4[t][lane];
#pragma unroll
      for (int r = 0; r < 4; ++r) {
        const float4 x4 = *(const float4*)&xrow[(size_t)r * D_ + 4 * t];  // uniform -> s_load
        acc[r][0] = fadd(acc[r][0], fmul(x4.x, m4.x));
        acc[r][1] = fadd(acc[r][1], fmul(x4.y, m4.y));
        acc[r][2] = fadd(acc[r][2], fmul(x4.z, m4.z));
        acc[r][3] = fadd(acc[r][3], fmul(x4.w, m4.w));
      }
    }

#pragma unroll
    for (int r = 0; r < 4; ++r) {
      // SSE3 hadd horizontal: (l0+l1)+(l2+l3)
      const float cosr = fadd(fadd(acc[r][0], acc[r][1]), fadd(acc[r][2], acc[r][3]));
      const float p = np_softmax64(cosr);
      p_ws[(((size_t)b << 12) + rowbase + r) * K_ + lane] = p;
    }
  }
}

// ============ LEGACY (fallback if ws too small): fused r11/r13 path ============
__global__ __launch_bounds__(1024, 1)
void xn_cos_softmax_legacy(const float* __restrict__ x,
                           const float4* __restrict__ mnT4_g,
                           float* __restrict__ p_ws) {
  __shared__ float4 mnT4[64][64];
  __shared__ float xst[16][4][XPAD];
  const int b = blockIdx.x;
  const int seg = blockIdx.y;
  const int tid = threadIdx.x;
  const int w = tid >> 6;
  const int lane = tid & 63;

#pragma unroll
  for (int i = 0; i < 4; ++i)
    ((float4*)mnT4)[tid * 4 + i] = mnT4_g[tid * 4 + i];
  __syncthreads();

  const int L16 = lane & 15;
  const int rowg = lane >> 4;

  float4 xr[4];
  {
    const int n0 = seg * 512 + w * 4;
#pragma unroll
    for (int r = 0; r < 4; ++r)
      xr[r] = *(const float4*)&x[(((size_t)b << 12) + n0 + r) * D_ + lane * 4];
  }

  for (int pass = 0; pass < 8; ++pass) {
    const int n0 = seg * 512 + pass * 64 + w * 4;
#pragma unroll
    for (int r = 0; r < 4; ++r)
      *(float4*)&xst[w][r][lane * 4] = xr[r];
    FENCE_LGKM();

    if (pass < 7) {
      const int n1 = n0 + 64;
#pragma unroll
      for (int r = 0; r < 4; ++r)
        xr[r] = *(const float4*)&x[(((size_t)b << 12) + n1 + r) * D_ + lane * 4];
    }

    float den4[4];
    {
      float den;
      np_norm4(&xst[w][rowg][0], L16, &den);
#pragma unroll
      for (int r = 0; r < 4; ++r) den4[r] = __shfl(den, 16 * r);
    }
    CBAR();

#pragma unroll
    for (int r = 0; r < 4; ++r) {
      float4 v = *(float4*)&xst[w][r][lane * 4];
      v.x = __fdiv_rn(v.x, den4[r]); v.y = __fdiv_rn(v.y, den4[r]);
      v.z = __fdiv_rn(v.z, den4[r]); v.w = __fdiv_rn(v.w, den4[r]);
      *(float4*)&xst[w][r][lane * 4] = v;
    }
    FENCE_LGKM();

    float acc[4][4];
#pragma unroll
    for (int r = 0; r < 4; ++r)
#pragma unroll
      for (int j = 0; j < 4; ++j) acc[r][j] = 0.f;

#pragma unroll 4
    for (int t = 0; t < 64; ++t) {
      const float4 m4 = mnT4[t][lane];
#pragma unroll
      for (int r = 0; r < 4; ++r) {
        const float4 x4 = *(const float4*)&xst[w][r][4 * t];
        acc[r][0] = fadd(acc[r][0], fmul(x4.x, m4.x));
        acc[r][1] = fadd(acc[r][1], fmul(x4.y, m4.y));
        acc[r][2] = fadd(acc[r][2], fmul(x4.z, m4.z));
        acc[r][3] = fadd(acc[r][3], fmul(x4.w, m4.w));
      }
    }

#pragma unroll
    for (int r = 0; r < 4; ++r) {
      const float cosr = fadd(fadd(acc[r][0], acc[r][1]), fadd(acc[r][2], acc[r][3]));
      const float p = np_softmax64(cosr);
      p_ws[(((size_t)b << 12) + n0 + r) * K_ + lane] = p;
    }
    CBAR();
  }
}

// ============ stage 2: numpy PAIRWISE f32 sum over n=4096 (leaf groups) ============
__global__ __launch_bounds__(256)
void pairwise_sum_n(const float* __restrict__ p_ws, float* __restrict__ s_part) {
  __shared__ float part[4][K_];
  const int b = blockIdx.x;
  const int g = blockIdx.y;
  const int w = threadIdx.x >> 6;
  const int k = threadIdx.x & 63;
  const float* base = p_ws + ((size_t)b << 12) * K_ + k;

  float l[2];
#pragma unroll 1
  for (int i = 0; i < 2; ++i) {
    const float* leaf = base + (size_t)(g * 8 + w * 2 + i) * 128 * K_;
    float c[16];
#pragma unroll
    for (int L = 0; L < 16; ++L) {
      const float* pL = leaf + (size_t)L * K_;
      const float q0 = pL[0 * 16 * K_];
      const float q1 = pL[1 * 16 * K_];
      const float q2 = pL[2 * 16 * K_];
      const float q3 = pL[3 * 16 * K_];
      const float q4 = pL[4 * 16 * K_];
      const float q5 = pL[5 * 16 * K_];
      const float q6 = pL[6 * 16 * K_];
      const float q7 = pL[7 * 16 * K_];
      c[L] = fadd(fadd(fadd(q0, q4), fadd(q1, q5)), fadd(fadd(q2, q6), fadd(q3, q7)));
    }
    float u8[8];
#pragma unroll
    for (int L = 0; L < 8; ++L) u8[L] = fadd(c[L], c[L + 8]);
    float v4[4];
#pragma unroll
    for (int L = 0; L < 4; ++L) v4[L] = fadd(u8[L], u8[L + 4]);
    l[i] = fadd(fadd(v4[0], v4[2]), fadd(v4[1], v4[3]));
  }
  part[w][k] = fadd(l[0], l[1]);
  __syncthreads();
  if (w == 0) {
    const float Sg = fadd(fadd(part[0][k], part[1][k]), fadd(part[2][k], part[3][k]));
    s_part[(b * 4 + g) * K_ + k] = Sg;
  }
}

// ============ root combine + bitwise final softmax -> top-8 -> sample ============
__global__ __launch_bounds__(256)
void topk_sample(const float* __restrict__ s_part,
                 const float* __restrict__ mu,
                 const float* __restrict__ ls,
                 float* __restrict__ out) {
  __shared__ float sv[K_];
  __shared__ int sidx[NS_];
  const int b = blockIdx.x;
  const int t = threadIdx.x;
  if (t < K_) {
    const float S0 = s_part[(b * 4 + 0) * K_ + t];
    const float S1 = s_part[(b * 4 + 1) * K_ + t];
    const float S2 = s_part[(b * 4 + 2) * K_ + t];
    const float S3 = s_part[(b * 4 + 3) * K_ + t];
    sv[t] = fadd(fadd(S0, S1), fadd(S2, S3));
  }
  __syncthreads();
  if (t == 0) {
    float mx = sv[0];
    for (int k = 1; k < K_; ++k) mx = fmaxf(mx, sv[k]);
    float e[K_];
    for (int k = 0; k < K_; ++k) e[k] = np_expf(__fsub_rn(sv[k], mx));
    const float denom = np_sum64(e);
    float rv[K_];
    for (int k = 0; k < K_; ++k) rv[k] = __fdiv_rn(e[k], denom);
    for (int q = 0; q < NS_; ++q) {
      float best = -1.0e30f; int bi = 0;
      for (int k = 0; k < K_; ++k) {
        if (rv[k] > best) { best = rv[k]; bi = k; }
      }
      sidx[q] = bi;
      rv[bi] = -1.0e30f;
    }
  }
  __syncthreads();

  const int q = t >> 5;
  const int d0 = (t & 31) * 8;
  const int k = sidx[q];
  const float* mrow = mu + k * D_ + d0;
  const float* lrow = ls + k * D_ + d0;
  float* orow = out + ((size_t)b * NS_ + q) * D_ + d0;
  const uint32_t ibase = (uint32_t)(((b * NS_) + q) * D_ + d0);
#pragma unroll
  for (int j = 0; j < 8; ++j) {
    const float z = jax_normal_from_index(ibase + (uint32_t)j);
    orow[j] = fmaf(expf(lrow[j]), z, mrow[j]);
  }
}

extern "C" void kernel_launch(void* const* d_in, const int* in_sizes, int n_in,
                              void* d_out, int out_size, void* d_ws, size_t ws_size,
                              hipStream_t stream) {
  const float* x  = (const float*)d_in[0];
  const float* mu = (const float*)d_in[1];
  const float* ls = (const float*)d_in[2];
  float* out = (float*)d_out;
  (void)in_sizes; (void)n_in; (void)out_size;

  const size_t XN_BYTES = (size_t)B_ * N_ * D_ * 4;   // 256 MiB
  const size_t P_BYTES  = (size_t)B_ * N_ * K_ * 4;   // 64 MiB
  const size_t NEED_T1  = XN_BYTES + P_BYTES + 65536 + 65536;

  if (ws_size >= NEED_T1) {
    // Tier-1: split path (xn precompute -> SMEM/LDS-split dot)
    float*  xn     = (float*)d_ws;
    float*  p_ws   = (float*)((char*)d_ws + XN_BYTES);
    float*  s_part = (float*)((char*)d_ws + XN_BYTES + P_BYTES);
    float4* mnT4   = (float4*)((char*)d_ws + XN_BYTES + P_BYTES + 65536);

    prep_mnT<<<1, 64, 0, stream>>>(mu, mnT4);
    dim3 gridA(B_, 8);
    xn_write<<<gridA, 1024, 0, stream>>>(x, xn);
    dim3 gridB(B_, 16);
    cos_softmax_xn<<<gridB, 512, 0, stream>>>(xn, mnT4, p_ws);
    dim3 grid2(B_, 4);
    pairwise_sum_n<<<grid2, 256, 0, stream>>>(p_ws, s_part);
    topk_sample<<<B_, 256, 0, stream>>>(s_part, mu, ls, out);
  } else {
    // Fallback: legacy fused path (67.2 MiB workspace)
    float*  p_ws   = (float*)d_ws;
    float*  s_part = (float*)((char*)d_ws + P_BYTES);
    float4* mnT4   = (float4*)((char*)d_ws + P_BYTES + 65536);

    prep_mnT<<<1, 64, 0, stream>>>(mu, mnT4);
    dim3 grid(B_, 8);
    xn_cos_softmax_legacy<<<grid, 1024, 0, stream>>>(x, mnT4, p_ws);
    dim3 grid2(B_, 4);
    pairwise_sum_n<<<grid2, 256, 0, stream>>>(p_ws, s_part);
    topk_sample<<<B_, 256, 0, stream>>>(s_part, mu, ls, out);
  }
}

// Round 17
// 349.660 us; speedup vs baseline: 3.1897x; 1.8062x over previous
//
#include <hip/hip_runtime.h>
#include <math.h>
#include <stdint.h>

#define B_ 64
#define N_ 4096
#define K_ 64
#define D_ 256
#define NS_ 8
#define XPAD 264

// wave-private LDS sync: HW DS ops are in-order per wave; the waitcnt gives
// write->read visibility, the "memory" clobber stops compiler reordering.
#define FENCE_LGKM() asm volatile("s_waitcnt lgkmcnt(0)" ::: "memory")
// WAR-only ordering (HW in-order per wave): compiler barrier suffices.
#define CBAR() asm volatile("" ::: "memory")

// ================= bitwise-IEEE helpers (no contraction) =================
__device__ __forceinline__ float fadd(float a, float b) { return __fadd_rn(a, b); }
__device__ __forceinline__ float fmul(float a, float b) { return __fmul_rn(a, b); }

// lane-broadcast via v_readlane (VALU pipe, no DS traffic); lane idx is a literal
__device__ __forceinline__ float rdlane(float v, int lane) {
  return __int_as_float(__builtin_amdgcn_readlane(__float_as_int(v), lane));
}

// numpy f32 SIMD exp (loops_exponent_log.dispatch, FMA/AVX512 targets)
__device__ __forceinline__ float np_expf(float x) {
  const float LOG2E = 1.442695040888963407359924681001892137f;
  float qf = rintf(__fmul_rn(x, LOG2E));
  float r = __fmaf_rn(qf, -6.93145752e-1f, x);   // NPY_CODY_WAITE_LOGE_2_HIGHf
  r = __fmaf_rn(qf, -1.42860677e-6f, r);         // NPY_CODY_WAITE_LOGE_2_LOWf
  float num = __fmaf_rn(r, 5.082762527590693718096e-04f, 6.757896990527504603057e-03f);
  num = __fmaf_rn(num, r, 5.114512081637298353406e-02f);
  num = __fmaf_rn(num, r, 2.473615434895520810817e-01f);
  num = __fmaf_rn(num, r, 7.257664613233124478488e-01f);
  num = __fmaf_rn(num, r, 9.999999999980870924916e-01f);
  float den = __fmaf_rn(r, 2.159509375685829852307e-02f, -2.742335390411667452936e-01f);
  den = __fmaf_rn(den, r, 1.000000000000000000000e+00f);
  float poly = __fdiv_rn(num, den);
  int qi = (int)qf;
  float scale = __int_as_float((127 + qi) << 23);
  return __fmul_rn(poly, scale);
}

// ================= JAX threefry2x32 (key=(0,42)), partitionable =================
__device__ __forceinline__ uint32_t rotl32(uint32_t x, int r) {
  return (x << r) | (x >> (32 - r));
}
__device__ __forceinline__ float jax_normal_from_index(uint32_t i) {
  uint32_t x0 = 0u, x1 = i;
  const uint32_t ks0 = 0u, ks1 = 42u, ks2 = 0x1BD11BDAu ^ 0u ^ 42u;
  x0 += ks0; x1 += ks1;
#define TF_ROUND(r) { x0 += x1; x1 = rotl32(x1, (r)); x1 ^= x0; }
  TF_ROUND(13) TF_ROUND(15) TF_ROUND(26) TF_ROUND(6)
  x0 += ks1; x1 += ks2 + 1u;
  TF_ROUND(17) TF_ROUND(29) TF_ROUND(16) TF_ROUND(24)
  x0 += ks2; x1 += ks0 + 2u;
  TF_ROUND(13) TF_ROUND(15) TF_ROUND(26) TF_ROUND(6)
  x0 += ks0; x1 += ks1 + 3u;
  TF_ROUND(17) TF_ROUND(29) TF_ROUND(16) TF_ROUND(24)
  x0 += ks1; x1 += ks2 + 4u;
  TF_ROUND(13) TF_ROUND(15) TF_ROUND(26) TF_ROUND(6)
  x0 += ks2; x1 += ks0 + 5u;
#undef TF_ROUND
  uint32_t bits = x0 ^ x1;
  uint32_t fb = (bits >> 9) | 0x3f800000u;
  float f = __uint_as_float(fb) - 1.0f;
  const float lo = __uint_as_float(0xBF7FFFFFu);
  float u = f * 2.0f + lo;
  u = fmaxf(lo, u);
  float w = -log1pf(-u * u);
  float p;
  if (w < 5.0f) {
    w = w - 2.5f;
    p = 2.81022636e-08f;
    p = fmaf(p, w, 3.43273939e-07f);
    p = fmaf(p, w, -3.5233877e-06f);
    p = fmaf(p, w, -4.39150654e-06f);
    p = fmaf(p, w, 0.00021858087f);
    p = fmaf(p, w, -0.00125372503f);
    p = fmaf(p, w, -0.00417768164f);
    p = fmaf(p, w, 0.246640727f);
    p = fmaf(p, w, 1.50140941f);
  } else {
    w = sqrtf(w) - 3.0f;
    p = -0.000200214257f;
    p = fmaf(p, w, 0.000100950558f);
    p = fmaf(p, w, 0.00134934322f);
    p = fmaf(p, w, -0.00367342844f);
    p = fmaf(p, w, 0.00573950773f);
    p = fmaf(p, w, -0.0076224613f);
    p = fmaf(p, w, 0.00943887047f);
    p = fmaf(p, w, 1.00167406f);
    p = fmaf(p, w, 2.83297682f);
  }
  return 1.41421356f * (p * u);
}

// numpy pairwise-128 of squares (AVX512)
__device__ __forceinline__ float np_pw128_sq(const float* p) {
  float t16[16];
#pragma unroll
  for (int L = 0; L < 16; ++L) {
    float q0 = p[L];       q0 = fmul(q0, q0);
    float q1 = p[L + 16];  q1 = fmul(q1, q1);
    float q2 = p[L + 32];  q2 = fmul(q2, q2);
    float q3 = p[L + 48];  q3 = fmul(q3, q3);
    float q4 = p[L + 64];  q4 = fmul(q4, q4);
    float q5 = p[L + 80];  q5 = fmul(q5, q5);
    float q6 = p[L + 96];  q6 = fmul(q6, q6);
    float q7 = p[L + 112]; q7 = fmul(q7, q7);
    t16[L] = fadd(fadd(fadd(q0, q4), fadd(q1, q5)), fadd(fadd(q2, q6), fadd(q3, q7)));
  }
  float u8[8];
#pragma unroll
  for (int L = 0; L < 8; ++L) u8[L] = fadd(t16[L], t16[L + 8]);
  float v4[4];
#pragma unroll
  for (int L = 0; L < 4; ++L) v4[L] = fadd(u8[L], u8[L + 4]);
  return fadd(fadd(v4[0], v4[2]), fadd(v4[1], v4[3]));
}

// numpy sum of 64 contiguous f32 (AVX512, n=64 one block)
__device__ __forceinline__ float np_sum64(const float* a) {
  float t16[16];
#pragma unroll
  for (int L = 0; L < 16; ++L)
    t16[L] = fadd(fadd(a[L], a[16 + L]), fadd(a[32 + L], a[48 + L]));
  float u8[8];
#pragma unroll
  for (int L = 0; L < 8; ++L) u8[L] = fadd(t16[L], t16[L + 8]);
  float v4[4];
#pragma unroll
  for (int L = 0; L < 4; ++L) v4[L] = fadd(u8[L], u8[L + 4]);
  return fadd(fadd(v4[0], v4[2]), fadd(v4[1], v4[3]));
}

// ============ prep: mn = mu / max(np_norm(mu_row), 1e-8), stored transposed ============
__global__ __launch_bounds__(64)
void prep_mnT(const float* __restrict__ mu, float4* __restrict__ mnT4) {
  const int k = threadIdx.x;
  const float* mrow = mu + k * D_;
  const float n2 = fadd(np_pw128_sq(mrow), np_pw128_sq(mrow + 128));
  const float den = fmaxf(__fsqrt_rn(n2), 1e-8f);
#pragma unroll 8
  for (int t = 0; t < 64; ++t) {
    float4 m = *(const float4*)&mrow[4 * t];
    float4 o;
    o.x = __fdiv_rn(m.x, den); o.y = __fdiv_rn(m.y, den);
    o.z = __fdiv_rn(m.z, den); o.w = __fdiv_rn(m.w, den);
    mnT4[t * K_ + k] = o;   // mnT4[t][k] = mn[k][4t..4t+3]
  }
}

// ================= numpy AVX512 norm of a staged row (16-lane trees) =================
__device__ __forceinline__ void np_norm4(const float* rowp, int L16, float* den_out) {
  float res2[2];
#pragma unroll
  for (int half = 0; half < 2; ++half) {
    const float* p = rowp + half * 128 + L16;
    float q0 = p[0];   q0 = fmul(q0, q0);
    float q1 = p[16];  q1 = fmul(q1, q1);
    float q2 = p[32];  q2 = fmul(q2, q2);
    float q3 = p[48];  q3 = fmul(q3, q3);
    float q4 = p[64];  q4 = fmul(q4, q4);
    float q5 = p[80];  q5 = fmul(q5, q5);
    float q6 = p[96];  q6 = fmul(q6, q6);
    float q7 = p[112]; q7 = fmul(q7, q7);
    const float t = fadd(fadd(fadd(q0, q4), fadd(q1, q5)),
                         fadd(fadd(q2, q6), fadd(q3, q7)));
    float u  = fadd(t, __shfl_xor(t, 8));
    float v  = fadd(u, __shfl_xor(u, 4));
    float w2 = fadd(v, __shfl_xor(v, 2));
    res2[half] = fadd(w2, __shfl_xor(w2, 1));
  }
  const float n2 = fadd(res2[0], res2[1]);
  *den_out = fmaxf(__fsqrt_rn(n2), 1e-8f);
}

// ================= numpy softmax over k=64 (lane = k) =================
__device__ __forceinline__ float np_softmax64(float cosr) {
  float mx = cosr;
  mx = fmaxf(mx, __shfl_xor(mx, 1));
  mx = fmaxf(mx, __shfl_xor(mx, 2));
  mx = fmaxf(mx, __shfl_xor(mx, 4));
  mx = fmaxf(mx, __shfl_xor(mx, 8));
  mx = fmaxf(mx, __shfl_xor(mx, 16));
  mx = fmaxf(mx, __shfl_xor(mx, 32));
  const float e = np_expf(__fsub_rn(cosr, mx));
  float g1 = fadd(e, __shfl_xor(e, 16));
  float g2 = fadd(g1, __shfl_xor(g1, 32));
  float u  = fadd(g2, __shfl_xor(g2, 8));
  float v  = fadd(u, __shfl_xor(u, 4));
  float w2 = fadd(v, __shfl_xor(v, 2));
  float sres = fadd(w2, __shfl_xor(w2, 1));
  const float denom = __shfl(sres, 0);
  return __fdiv_rn(e, denom);
}

// ============ main: np-norm xn -> np-einsum cos -> np softmax -> p[b][n][k] ============
// grid (64 b, 8 seg), block 1024 (16 waves). Wave w: 4 rows/pass, 8 passes.
// LDS used for: mnT4 (read-only) + x staging for the NORM phase only.
// Dot x-operand comes from registers via v_readlane (VALU) -> DS ops/pass: 364 -> ~100.
__global__ __launch_bounds__(1024, 1)
void xn_cos_softmax(const float* __restrict__ x,
                    const float4* __restrict__ mnT4_g,
                    float* __restrict__ p_ws) {
  __shared__ float4 mnT4[64][64];       // [t][k]  64 KiB
  __shared__ float xst[16][4][XPAD];    // per-wave 4 staged rows (norm phase only)

  const int b = blockIdx.x;
  const int seg = blockIdx.y;
  const int tid = threadIdx.x;
  const int w = tid >> 6;
  const int lane = tid & 63;

#pragma unroll
  for (int i = 0; i < 4; ++i)
    ((float4*)mnT4)[tid * 4 + i] = mnT4_g[tid * 4 + i];
  __syncthreads();   // the only block barrier: mnT4 ready

  const int L16 = lane & 15;
  const int rowg = lane >> 4;

  // preload pass 0 rows into registers (lane slice d = 4*lane..4*lane+3)
  float4 xr[4];
  {
    const int n0 = seg * 512 + w * 4;
#pragma unroll
    for (int r = 0; r < 4; ++r)
      xr[r] = *(const float4*)&x[(((size_t)b << 12) + n0 + r) * D_ + lane * 4];
  }

  for (int pass = 0; pass < 8; ++pass) {
    const int n0 = seg * 512 + pass * 64 + w * 4;

    // ---- stage 4 rows for the norm phase ----
#pragma unroll
    for (int r = 0; r < 4; ++r)
      *(float4*)&xst[w][r][lane * 4] = xr[r];
    FENCE_LGKM();   // RAW: stage writes -> cross-lane norm reads

    // ---- numpy AVX512 pairwise norm per row (4 rows x 16 lanes) ----
    float den4[4];
    {
      float den;
      np_norm4(&xst[w][rowg][0], L16, &den);   // valid at lanes 0,16,32,48
#pragma unroll
      for (int r = 0; r < 4; ++r) den4[r] = __shfl(den, 16 * r);
    }
    CBAR();   // WAR: norm reads ordered before NEXT pass's stage writes

    // ---- xn in REGISTERS (same bits as LDS round-trip: xr == staged value) ----
    float4 xnr[4];
#pragma unroll
    for (int r = 0; r < 4; ++r) {
      xnr[r].x = __fdiv_rn(xr[r].x, den4[r]);
      xnr[r].y = __fdiv_rn(xr[r].y, den4[r]);
      xnr[r].z = __fdiv_rn(xr[r].z, den4[r]);
      xnr[r].w = __fdiv_rn(xr[r].w, den4[r]);
    }

    // ---- issue next pass's global loads (overlaps the dot) ----
    if (pass < 7) {
      const int n1 = n0 + 64;
#pragma unroll
      for (int r = 0; r < 4; ++r)
        xr[r] = *(const float4*)&x[(((size_t)b << 12) + n1 + r) * D_ + lane * 4];
    }

    // ---- dot: numpy einsum (no FMA, seq 4-blocks, t ascending) ----
    // x4 of step t lives in lane t's xnr slice -> v_readlane (literal lane idx).
    float acc[4][4];
#pragma unroll
    for (int r = 0; r < 4; ++r)
#pragma unroll
      for (int j = 0; j < 4; ++j) acc[r][j] = 0.f;

#pragma unroll
    for (int t = 0; t < 64; ++t) {
      const float4 m4 = mnT4[t][lane];
#pragma unroll
      for (int r = 0; r < 4; ++r) {
        const float x0 = rdlane(xnr[r].x, t);
        const float x1 = rdlane(xnr[r].y, t);
        const float x2 = rdlane(xnr[r].z, t);
        const float x3 = rdlane(xnr[r].w, t);
        acc[r][0] = fadd(acc[r][0], fmul(x0, m4.x));
        acc[r][1] = fadd(acc[r][1], fmul(x1, m4.y));
        acc[r][2] = fadd(acc[r][2], fmul(x2, m4.z));
        acc[r][3] = fadd(acc[r][3], fmul(x3, m4.w));
      }
    }

    // ---- per-row softmax over k (lane = k), numpy semantics ----
#pragma unroll
    for (int r = 0; r < 4; ++r) {
      // SSE3 hadd horizontal: (l0+l1)+(l2+l3)
      const float cosr = fadd(fadd(acc[r][0], acc[r][1]), fadd(acc[r][2], acc[r][3]));
      const float p = np_softmax64(cosr);
      p_ws[(((size_t)b << 12) + n0 + r) * K_ + lane] = p;
    }
  }
}

// ============ stage 2: numpy PAIRWISE f32 sum over n=4096 (leaf groups) ============
__global__ __launch_bounds__(256)
void pairwise_sum_n(const float* __restrict__ p_ws, float* __restrict__ s_part) {
  __shared__ float part[4][K_];
  const int b = blockIdx.x;
  const int g = blockIdx.y;
  const int w = threadIdx.x >> 6;
  const int k = threadIdx.x & 63;
  const float* base = p_ws + ((size_t)b << 12) * K_ + k;

  float l[2];
#pragma unroll 1
  for (int i = 0; i < 2; ++i) {
    const float* leaf = base + (size_t)(g * 8 + w * 2 + i) * 128 * K_;
    float c[16];
#pragma unroll
    for (int L = 0; L < 16; ++L) {
      const float* pL = leaf + (size_t)L * K_;
      const float q0 = pL[0 * 16 * K_];
      const float q1 = pL[1 * 16 * K_];
      const float q2 = pL[2 * 16 * K_];
      const float q3 = pL[3 * 16 * K_];
      const float q4 = pL[4 * 16 * K_];
      const float q5 = pL[5 * 16 * K_];
      const float q6 = pL[6 * 16 * K_];
      const float q7 = pL[7 * 16 * K_];
      c[L] = fadd(fadd(fadd(q0, q4), fadd(q1, q5)), fadd(fadd(q2, q6), fadd(q3, q7)));
    }
    float u8[8];
#pragma unroll
    for (int L = 0; L < 8; ++L) u8[L] = fadd(c[L], c[L + 8]);
    float v4[4];
#pragma unroll
    for (int L = 0; L < 4; ++L) v4[L] = fadd(u8[L], u8[L + 4]);
    l[i] = fadd(fadd(v4[0], v4[2]), fadd(v4[1], v4[3]));
  }
  part[w][k] = fadd(l[0], l[1]);   // l_{2w} + l_{2w+1}
  __syncthreads();
  if (w == 0) {
    const float Sg = fadd(fadd(part[0][k], part[1][k]), fadd(part[2][k], part[3][k]));
    s_part[(b * 4 + g) * K_ + k] = Sg;
  }
}

// ============ root combine + bitwise final softmax -> top-8 -> sample ============
__global__ __launch_bounds__(256)
void topk_sample(const float* __restrict__ s_part,
                 const float* __restrict__ mu,
                 const float* __restrict__ ls,
                 float* __restrict__ out) {
  __shared__ float sv[K_];
  __shared__ int sidx[NS_];
  const int b = blockIdx.x;
  const int t = threadIdx.x;
  if (t < K_) {
    const float S0 = s_part[(b * 4 + 0) * K_ + t];
    const float S1 = s_part[(b * 4 + 1) * K_ + t];
    const float S2 = s_part[(b * 4 + 2) * K_ + t];
    const float S3 = s_part[(b * 4 + 3) * K_ + t];
    sv[t] = fadd(fadd(S0, S1), fadd(S2, S3));   // pairwise root
  }
  __syncthreads();
  if (t == 0) {
    float mx = sv[0];
    for (int k = 1; k < K_; ++k) mx = fmaxf(mx, sv[k]);
    float e[K_];
    for (int k = 0; k < K_; ++k) e[k] = np_expf(__fsub_rn(sv[k], mx));
    const float denom = np_sum64(e);
    float rv[K_];
    for (int k = 0; k < K_; ++k) rv[k] = __fdiv_rn(e[k], denom);
    for (int q = 0; q < NS_; ++q) {
      float best = -1.0e30f; int bi = 0;
      for (int k = 0; k < K_; ++k) {
        if (rv[k] > best) { best = rv[k]; bi = k; }
      }
      sidx[q] = bi;
      rv[bi] = -1.0e30f;
    }
  }
  __syncthreads();

  const int q = t >> 5;
  const int d0 = (t & 31) * 8;
  const int k = sidx[q];
  const float* mrow = mu + k * D_ + d0;
  const float* lrow = ls + k * D_ + d0;
  float* orow = out + ((size_t)b * NS_ + q) * D_ + d0;
  const uint32_t ibase = (uint32_t)(((b * NS_) + q) * D_ + d0);
#pragma unroll
  for (int j = 0; j < 8; ++j) {
    const float z = jax_normal_from_index(ibase + (uint32_t)j);
    orow[j] = fmaf(expf(lrow[j]), z, mrow[j]);
  }
}

extern "C" void kernel_launch(void* const* d_in, const int* in_sizes, int n_in,
                              void* d_out, int out_size, void* d_ws, size_t ws_size,
                              hipStream_t stream) {
  const float* x  = (const float*)d_in[0];
  const float* mu = (const float*)d_in[1];
  const float* ls = (const float*)d_in[2];
  float* out = (float*)d_out;
  (void)ws_size; (void)in_sizes; (void)n_in; (void)out_size;

  float*  p_ws   = (float*)d_ws;                                   // 64 MiB
  float*  s_part = (float*)((char*)d_ws + (size_t)67108864);       // 64 KiB
  float4* mnT4   = (float4*)((char*)d_ws + (size_t)67174400);      // 64 KiB

  prep_mnT<<<1, 64, 0, stream>>>(mu, mnT4);
  dim3 grid(B_, 8);
  xn_cos_softmax<<<grid, 1024, 0, stream>>>(x, mnT4, p_ws);
  dim3 grid2(B_, 4);
  pairwise_sum_n<<<grid2, 256, 0, stream>>>(p_ws, s_part);
  topk_sample<<<B_, 256, 0, stream>>>(s_part, mu, ls, out);
}

// Round 18
// 304.448 us; speedup vs baseline: 3.6634x; 1.1485x over previous
//
#include <hip/hip_runtime.h>
#include <math.h>
#include <stdint.h>

#define B_ 64
#define N_ 4096
#define K_ 64
#define D_ 256
#define NS_ 8
#define XPAD 264   // row offsets 0/8/16/24 banks -> max 2-way aliasing in norm phase (free)

// wave-private LDS sync: HW DS ops are in-order per wave; the waitcnt gives
// write->read visibility, the "memory" clobber stops compiler reordering.
#define FENCE_LGKM() asm volatile("s_waitcnt lgkmcnt(0)" ::: "memory")
// WAR-only ordering (HW in-order per wave): compiler barrier suffices.
#define CBAR() asm volatile("" ::: "memory")

// ================= bitwise-IEEE helpers (no contraction) =================
__device__ __forceinline__ float fadd(float a, float b) { return __fadd_rn(a, b); }
__device__ __forceinline__ float fmul(float a, float b) { return __fmul_rn(a, b); }

// numpy f32 SIMD exp (loops_exponent_log.dispatch, FMA/AVX512 targets)
__device__ __forceinline__ float np_expf(float x) {
  const float LOG2E = 1.442695040888963407359924681001892137f;
  float qf = rintf(__fmul_rn(x, LOG2E));
  float r = __fmaf_rn(qf, -6.93145752e-1f, x);   // NPY_CODY_WAITE_LOGE_2_HIGHf
  r = __fmaf_rn(qf, -1.42860677e-6f, r);         // NPY_CODY_WAITE_LOGE_2_LOWf
  float num = __fmaf_rn(r, 5.082762527590693718096e-04f, 6.757896990527504603057e-03f);
  num = __fmaf_rn(num, r, 5.114512081637298353406e-02f);
  num = __fmaf_rn(num, r, 2.473615434895520810817e-01f);
  num = __fmaf_rn(num, r, 7.257664613233124478488e-01f);
  num = __fmaf_rn(num, r, 9.999999999980870924916e-01f);
  float den = __fmaf_rn(r, 2.159509375685829852307e-02f, -2.742335390411667452936e-01f);
  den = __fmaf_rn(den, r, 1.000000000000000000000e+00f);
  float poly = __fdiv_rn(num, den);
  int qi = (int)qf;
  float scale = __int_as_float((127 + qi) << 23);
  return __fmul_rn(poly, scale);
}

// ================= JAX threefry2x32 (key=(0,42)), partitionable =================
__device__ __forceinline__ uint32_t rotl32(uint32_t x, int r) {
  return (x << r) | (x >> (32 - r));
}
__device__ __forceinline__ float jax_normal_from_index(uint32_t i) {
  uint32_t x0 = 0u, x1 = i;
  const uint32_t ks0 = 0u, ks1 = 42u, ks2 = 0x1BD11BDAu ^ 0u ^ 42u;
  x0 += ks0; x1 += ks1;
#define TF_ROUND(r) { x0 += x1; x1 = rotl32(x1, (r)); x1 ^= x0; }
  TF_ROUND(13) TF_ROUND(15) TF_ROUND(26) TF_ROUND(6)
  x0 += ks1; x1 += ks2 + 1u;
  TF_ROUND(17) TF_ROUND(29) TF_ROUND(16) TF_ROUND(24)
  x0 += ks2; x1 += ks0 + 2u;
  TF_ROUND(13) TF_ROUND(15) TF_ROUND(26) TF_ROUND(6)
  x0 += ks0; x1 += ks1 + 3u;
  TF_ROUND(17) TF_ROUND(29) TF_ROUND(16) TF_ROUND(24)
  x0 += ks1; x1 += ks2 + 4u;
  TF_ROUND(13) TF_ROUND(15) TF_ROUND(26) TF_ROUND(6)
  x0 += ks2; x1 += ks0 + 5u;
#undef TF_ROUND
  uint32_t bits = x0 ^ x1;
  uint32_t fb = (bits >> 9) | 0x3f800000u;
  float f = __uint_as_float(fb) - 1.0f;
  const float lo = __uint_as_float(0xBF7FFFFFu);
  float u = f * 2.0f + lo;
  u = fmaxf(lo, u);
  float w = -log1pf(-u * u);
  float p;
  if (w < 5.0f) {
    w = w - 2.5f;
    p = 2.81022636e-08f;
    p = fmaf(p, w, 3.43273939e-07f);
    p = fmaf(p, w, -3.5233877e-06f);
    p = fmaf(p, w, -4.39150654e-06f);
    p = fmaf(p, w, 0.00021858087f);
    p = fmaf(p, w, -0.00125372503f);
    p = fmaf(p, w, -0.00417768164f);
    p = fmaf(p, w, 0.246640727f);
    p = fmaf(p, w, 1.50140941f);
  } else {
    w = sqrtf(w) - 3.0f;
    p = -0.000200214257f;
    p = fmaf(p, w, 0.000100950558f);
    p = fmaf(p, w, 0.00134934322f);
    p = fmaf(p, w, -0.00367342844f);
    p = fmaf(p, w, 0.00573950773f);
    p = fmaf(p, w, -0.0076224613f);
    p = fmaf(p, w, 0.00943887047f);
    p = fmaf(p, w, 1.00167406f);
    p = fmaf(p, w, 2.83297682f);
  }
  return 1.41421356f * (p * u);
}

// numpy pairwise-128 of squares (AVX512)
__device__ __forceinline__ float np_pw128_sq(const float* p) {
  float t16[16];
#pragma unroll
  for (int L = 0; L < 16; ++L) {
    float q0 = p[L];       q0 = fmul(q0, q0);
    float q1 = p[L + 16];  q1 = fmul(q1, q1);
    float q2 = p[L + 32];  q2 = fmul(q2, q2);
    float q3 = p[L + 48];  q3 = fmul(q3, q3);
    float q4 = p[L + 64];  q4 = fmul(q4, q4);
    float q5 = p[L + 80];  q5 = fmul(q5, q5);
    float q6 = p[L + 96];  q6 = fmul(q6, q6);
    float q7 = p[L + 112]; q7 = fmul(q7, q7);
    t16[L] = fadd(fadd(fadd(q0, q4), fadd(q1, q5)), fadd(fadd(q2, q6), fadd(q3, q7)));
  }
  float u8[8];
#pragma unroll
  for (int L = 0; L < 8; ++L) u8[L] = fadd(t16[L], t16[L + 8]);
  float v4[4];
#pragma unroll
  for (int L = 0; L < 4; ++L) v4[L] = fadd(u8[L], u8[L + 4]);
  return fadd(fadd(v4[0], v4[2]), fadd(v4[1], v4[3]));
}

// numpy sum of 64 contiguous f32 (AVX512, n=64 one block)
__device__ __forceinline__ float np_sum64(const float* a) {
  float t16[16];
#pragma unroll
  for (int L = 0; L < 16; ++L)
    t16[L] = fadd(fadd(a[L], a[16 + L]), fadd(a[32 + L], a[48 + L]));
  float u8[8];
#pragma unroll
  for (int L = 0; L < 8; ++L) u8[L] = fadd(t16[L], t16[L + 8]);
  float v4[4];
#pragma unroll
  for (int L = 0; L < 4; ++L) v4[L] = fadd(u8[L], u8[L + 4]);
  return fadd(fadd(v4[0], v4[2]), fadd(v4[1], v4[3]));
}

// ============ prep: mn = mu / max(np_norm(mu_row), 1e-8), stored transposed ============
__global__ __launch_bounds__(64)
void prep_mnT(const float* __restrict__ mu, float4* __restrict__ mnT4) {
  const int k = threadIdx.x;
  const float* mrow = mu + k * D_;
  const float n2 = fadd(np_pw128_sq(mrow), np_pw128_sq(mrow + 128));
  const float den = fmaxf(__fsqrt_rn(n2), 1e-8f);
#pragma unroll 8
  for (int t = 0; t < 64; ++t) {
    float4 m = *(const float4*)&mrow[4 * t];
    float4 o;
    o.x = __fdiv_rn(m.x, den); o.y = __fdiv_rn(m.y, den);
    o.z = __fdiv_rn(m.z, den); o.w = __fdiv_rn(m.w, den);
    mnT4[t * K_ + k] = o;   // mnT4[t][k] = mn[k][4t..4t+3]
  }
}

// ============ dot (64 t-chunks) with interleaved softmax of PREVIOUS pass ============
// Arithmetic identical to the serial version: only instruction placement differs.
// 14 chain steps injected between 16 dot chunks; each shfl issued one chunk
// before its use -> DS latency hides under dot VALU.
__device__ __forceinline__ void dot_pass_prev(
    const float* __restrict__ xstw,          // &xst[w][0][0], row stride XPAD
    const float4 (* __restrict__ mnT4)[64],  // [t][k]
    int lane,
    float (&acc)[4][4],
    const float (&accP)[4][4],
    float* __restrict__ pPrev)               // prev-pass store base (+= r*K_)
{
  float cosP[4], mP[4], tP[4], eP[4], gP[4], denomP[4];
#pragma unroll
  for (int tc = 0; tc < 16; ++tc) {
#pragma unroll
    for (int tt = 0; tt < 4; ++tt) {
      const int t = tc * 4 + tt;
      const float4 m4 = mnT4[t][lane];
#pragma unroll
      for (int r = 0; r < 4; ++r) {
        const float4 x4 = *(const float4*)&xstw[r * XPAD + 4 * t];
        acc[r][0] = fadd(acc[r][0], fmul(x4.x, m4.x));
        acc[r][1] = fadd(acc[r][1], fmul(x4.y, m4.y));
        acc[r][2] = fadd(acc[r][2], fmul(x4.z, m4.z));
        acc[r][3] = fadd(acc[r][3], fmul(x4.w, m4.w));
      }
    }
    // ---- softmax chain step tc (prev pass), numpy semantics ----
    if (tc == 0) {
#pragma unroll
      for (int r = 0; r < 4; ++r) {
        cosP[r] = fadd(fadd(accP[r][0], accP[r][1]), fadd(accP[r][2], accP[r][3]));
        mP[r] = cosP[r];
        tP[r] = __shfl_xor(mP[r], 1);
      }
    } else if (tc == 1) {
#pragma unroll
      for (int r = 0; r < 4; ++r) { mP[r] = fmaxf(mP[r], tP[r]); tP[r] = __shfl_xor(mP[r], 2); }
    } else if (tc == 2) {
#pragma unroll
      for (int r = 0; r < 4; ++r) { mP[r] = fmaxf(mP[r], tP[r]); tP[r] = __shfl_xor(mP[r], 4); }
    } else if (tc == 3) {
#pragma unroll
      for (int r = 0; r < 4; ++r) { mP[r] = fmaxf(mP[r], tP[r]); tP[r] = __shfl_xor(mP[r], 8); }
    } else if (tc == 4) {
#pragma unroll
      for (int r = 0; r < 4; ++r) { mP[r] = fmaxf(mP[r], tP[r]); tP[r] = __shfl_xor(mP[r], 16); }
    } else if (tc == 5) {
#pragma unroll
      for (int r = 0; r < 4; ++r) { mP[r] = fmaxf(mP[r], tP[r]); tP[r] = __shfl_xor(mP[r], 32); }
    } else if (tc == 6) {
#pragma unroll
      for (int r = 0; r < 4; ++r) {
        mP[r] = fmaxf(mP[r], tP[r]);
        eP[r] = np_expf(__fsub_rn(cosP[r], mP[r]));
      }
    } else if (tc == 7) {
#pragma unroll
      for (int r = 0; r < 4; ++r) tP[r] = __shfl_xor(eP[r], 16);
    } else if (tc == 8) {
#pragma unroll
      for (int r = 0; r < 4; ++r) { gP[r] = fadd(eP[r], tP[r]); tP[r] = __shfl_xor(gP[r], 32); }
    } else if (tc == 9) {
#pragma unroll
      for (int r = 0; r < 4; ++r) { gP[r] = fadd(gP[r], tP[r]); tP[r] = __shfl_xor(gP[r], 8); }
    } else if (tc == 10) {
#pragma unroll
      for (int r = 0; r < 4; ++r) { gP[r] = fadd(gP[r], tP[r]); tP[r] = __shfl_xor(gP[r], 4); }
    } else if (tc == 11) {
#pragma unroll
      for (int r = 0; r < 4; ++r) { gP[r] = fadd(gP[r], tP[r]); tP[r] = __shfl_xor(gP[r], 2); }
    } else if (tc == 12) {
#pragma unroll
      for (int r = 0; r < 4; ++r) { gP[r] = fadd(gP[r], tP[r]); tP[r] = __shfl_xor(gP[r], 1); }
    } else if (tc == 13) {
#pragma unroll
      for (int r = 0; r < 4; ++r) { gP[r] = fadd(gP[r], tP[r]); denomP[r] = __shfl(gP[r], 0); }
    } else if (tc == 14) {
#pragma unroll
      for (int r = 0; r < 4; ++r) pPrev[r * K_] = __fdiv_rn(eP[r], denomP[r]);
    }
  }
}

// plain softmax (epilogue for the final pass) — identical op order
__device__ __forceinline__ void softmax_store(const float (&accP)[4][4], float* pdst) {
#pragma unroll
  for (int r = 0; r < 4; ++r) {
    const float cosr = fadd(fadd(accP[r][0], accP[r][1]), fadd(accP[r][2], accP[r][3]));
    float mx = cosr;
    mx = fmaxf(mx, __shfl_xor(mx, 1));
    mx = fmaxf(mx, __shfl_xor(mx, 2));
    mx = fmaxf(mx, __shfl_xor(mx, 4));
    mx = fmaxf(mx, __shfl_xor(mx, 8));
    mx = fmaxf(mx, __shfl_xor(mx, 16));
    mx = fmaxf(mx, __shfl_xor(mx, 32));
    const float e = np_expf(__fsub_rn(cosr, mx));
    float g1 = fadd(e, __shfl_xor(e, 16));
    float g2 = fadd(g1, __shfl_xor(g1, 32));
    float u  = fadd(g2, __shfl_xor(g2, 8));
    float v  = fadd(u, __shfl_xor(u, 4));
    float w2 = fadd(v, __shfl_xor(v, 2));
    float sres = fadd(w2, __shfl_xor(w2, 1));
    const float denom = __shfl(sres, 0);
    pdst[r * K_] = __fdiv_rn(e, denom);
  }
}

// ============ main: np-norm xn -> np-einsum cos -> np softmax -> p[b][n][k] ============
// grid (64 b, 8 seg), block 1024 (16 waves). Wave w: 4 rows/pass, 8 passes.
// Softmax of pass t is pipelined into pass t+1's dot (wave-private xst, no block barriers).
__global__ __launch_bounds__(1024, 1)
void xn_cos_softmax(const float* __restrict__ x,
                    const float4* __restrict__ mnT4_g,
                    float* __restrict__ p_ws,
                    float* __restrict__ scr) {
  __shared__ float4 mnT4[64][64];       // [t][k]  64 KiB (block-shared, read-only)
  __shared__ float xst[16][4][XPAD];    // per-wave 4 staged rows, padded

  const int b = blockIdx.x;
  const int seg = blockIdx.y;
  const int tid = threadIdx.x;
  const int w = tid >> 6;
  const int lane = tid & 63;

#pragma unroll
  for (int i = 0; i < 4; ++i)
    ((float4*)mnT4)[tid * 4 + i] = mnT4_g[tid * 4 + i];
  __syncthreads();   // the only block barrier: mnT4 ready

  const int L16 = lane & 15;
  const int rowg = lane >> 4;   // 0..3 : row this lane-group handles in norm phase

  // preload pass 0 rows into registers
  float4 xr[4];
  {
    const int n0 = seg * 512 + w * 4;
#pragma unroll
    for (int r = 0; r < 4; ++r)
      xr[r] = *(const float4*)&x[(((size_t)b << 12) + n0 + r) * D_ + lane * 4];
  }

  float acc[4][4], accP[4][4];
#pragma unroll
  for (int r = 0; r < 4; ++r)
#pragma unroll
    for (int j = 0; j < 4; ++j) accP[r][j] = 0.f;
  float* pPrev = scr + lane;   // pass-0 dummy chain writes benign values to scratch

  for (int pass = 0; pass < 8; ++pass) {
    const int n0 = seg * 512 + pass * 64 + w * 4;

    // ---- stage 4 rows from prefetch registers ----
#pragma unroll
    for (int r = 0; r < 4; ++r)
      *(float4*)&xst[w][r][lane * 4] = xr[r];
    FENCE_LGKM();   // RAW: stage writes -> cross-lane norm reads

    // ---- issue next pass's global loads (hidden under compute) ----
    if (pass < 7) {
      const int n1 = n0 + 64;
#pragma unroll
      for (int r = 0; r < 4; ++r)
        xr[r] = *(const float4*)&x[(((size_t)b << 12) + n1 + r) * D_ + lane * 4];
    }

    // ---- numpy AVX512 pairwise norm per row (4 rows x 16 lanes) ----
    float den4[4];
    {
      const float* rowp = &xst[w][rowg][0];
      float res2[2];
#pragma unroll
      for (int half = 0; half < 2; ++half) {
        const float* p = rowp + half * 128 + L16;
        float q0 = p[0];   q0 = fmul(q0, q0);
        float q1 = p[16];  q1 = fmul(q1, q1);
        float q2 = p[32];  q2 = fmul(q2, q2);
        float q3 = p[48];  q3 = fmul(q3, q3);
        float q4 = p[64];  q4 = fmul(q4, q4);
        float q5 = p[80];  q5 = fmul(q5, q5);
        float q6 = p[96];  q6 = fmul(q6, q6);
        float q7 = p[112]; q7 = fmul(q7, q7);
        const float t = fadd(fadd(fadd(q0, q4), fadd(q1, q5)),
                             fadd(fadd(q2, q6), fadd(q3, q7)));
        float u  = fadd(t, __shfl_xor(t, 8));
        float v  = fadd(u, __shfl_xor(u, 4));
        float w2 = fadd(v, __shfl_xor(v, 2));
        res2[half] = fadd(w2, __shfl_xor(w2, 1));   // numpy value at L16==0
      }
      const float n2 = fadd(res2[0], res2[1]);
      const float den = fmaxf(__fsqrt_rn(n2), 1e-8f);  // valid at lanes 0,16,32,48
#pragma unroll
      for (int r = 0; r < 4; ++r) den4[r] = __shfl(den, 16 * r);
    }
    CBAR();   // WAR: norm reads ordered before divide writes (HW in-order per wave)

    // ---- xn = x / den (lane-private elements, in place) ----
#pragma unroll
    for (int r = 0; r < 4; ++r) {
      float4 v = *(float4*)&xst[w][r][lane * 4];
      v.x = __fdiv_rn(v.x, den4[r]); v.y = __fdiv_rn(v.y, den4[r]);
      v.z = __fdiv_rn(v.z, den4[r]); v.w = __fdiv_rn(v.w, den4[r]);
      *(float4*)&xst[w][r][lane * 4] = v;
    }
    FENCE_LGKM();   // RAW: divide writes -> broadcast dot reads

    // ---- dot(t) with interleaved softmax(t-1) ----
#pragma unroll
    for (int r = 0; r < 4; ++r)
#pragma unroll
      for (int j = 0; j < 4; ++j) acc[r][j] = 0.f;

    dot_pass_prev(&xst[w][0][0], mnT4, lane, acc, accP, pPrev);

#pragma unroll
    for (int r = 0; r < 4; ++r)
#pragma unroll
      for (int j = 0; j < 4; ++j) accP[r][j] = acc[r][j];
    pPrev = p_ws + (((size_t)b << 12) + n0) * K_ + lane;

    CBAR();   // WAR: dot reads ordered before next pass's stage writes
  }

  // epilogue: softmax + store for the final pass
  softmax_store(accP, pPrev);
}

// ============ stage 2: numpy PAIRWISE f32 sum over n=4096 (leaf groups) ============
// grid (64 b, 4 g), block 256 (4 waves). Wave w handles leaves 8g+2w, 8g+2w+1.
__global__ __launch_bounds__(256)
void pairwise_sum_n(const float* __restrict__ p_ws, float* __restrict__ s_part) {
  __shared__ float part[4][K_];
  const int b = blockIdx.x;
  const int g = blockIdx.y;
  const int w = threadIdx.x >> 6;
  const int k = threadIdx.x & 63;
  const float* base = p_ws + ((size_t)b << 12) * K_ + k;

  float l[2];
#pragma unroll 1
  for (int i = 0; i < 2; ++i) {
    const float* leaf = base + (size_t)(g * 8 + w * 2 + i) * 128 * K_;
    float c[16];
#pragma unroll
    for (int L = 0; L < 16; ++L) {
      const float* pL = leaf + (size_t)L * K_;
      const float q0 = pL[0 * 16 * K_];
      const float q1 = pL[1 * 16 * K_];
      const float q2 = pL[2 * 16 * K_];
      const float q3 = pL[3 * 16 * K_];
      const float q4 = pL[4 * 16 * K_];
      const float q5 = pL[5 * 16 * K_];
      const float q6 = pL[6 * 16 * K_];
      const float q7 = pL[7 * 16 * K_];
      c[L] = fadd(fadd(fadd(q0, q4), fadd(q1, q5)), fadd(fadd(q2, q6), fadd(q3, q7)));
    }
    float u8[8];
#pragma unroll
    for (int L = 0; L < 8; ++L) u8[L] = fadd(c[L], c[L + 8]);
    float v4[4];
#pragma unroll
    for (int L = 0; L < 4; ++L) v4[L] = fadd(u8[L], u8[L + 4]);
    l[i] = fadd(fadd(v4[0], v4[2]), fadd(v4[1], v4[3]));
  }
  part[w][k] = fadd(l[0], l[1]);   // l_{2w} + l_{2w+1}
  __syncthreads();
  if (w == 0) {
    const float Sg = fadd(fadd(part[0][k], part[1][k]), fadd(part[2][k], part[3][k]));
    s_part[(b * 4 + g) * K_ + k] = Sg;
  }
}

// ============ root combine + bitwise final softmax -> top-8 -> sample ============
__global__ __launch_bounds__(256)
void topk_sample(const float* __restrict__ s_part,
                 const float* __restrict__ mu,
                 const float* __restrict__ ls,
                 float* __restrict__ out) {
  __shared__ float sv[K_];
  __shared__ int sidx[NS_];
  const int b = blockIdx.x;
  const int t = threadIdx.x;
  if (t < K_) {
    const float S0 = s_part[(b * 4 + 0) * K_ + t];
    const float S1 = s_part[(b * 4 + 1) * K_ + t];
    const float S2 = s_part[(b * 4 + 2) * K_ + t];
    const float S3 = s_part[(b * 4 + 3) * K_ + t];
    sv[t] = fadd(fadd(S0, S1), fadd(S2, S3));   // pairwise root
  }
  __syncthreads();
  if (t == 0) {
    float mx = sv[0];
    for (int k = 1; k < K_; ++k) mx = fmaxf(mx, sv[k]);
    float e[K_];
    for (int k = 0; k < K_; ++k) e[k] = np_expf(__fsub_rn(sv[k], mx));
    const float denom = np_sum64(e);
    float rv[K_];
    for (int k = 0; k < K_; ++k) rv[k] = __fdiv_rn(e[k], denom);
    for (int q = 0; q < NS_; ++q) {
      float best = -1.0e30f; int bi = 0;
      for (int k = 0; k < K_; ++k) {
        if (rv[k] > best) { best = rv[k]; bi = k; }
      }
      sidx[q] = bi;
      rv[bi] = -1.0e30f;
    }
  }
  __syncthreads();

  const int q = t >> 5;
  const int d0 = (t & 31) * 8;
  const int k = sidx[q];
  const float* mrow = mu + k * D_ + d0;
  const float* lrow = ls + k * D_ + d0;
  float* orow = out + ((size_t)b * NS_ + q) * D_ + d0;
  const uint32_t ibase = (uint32_t)(((b * NS_) + q) * D_ + d0);
#pragma unroll
  for (int j = 0; j < 8; ++j) {
    const float z = jax_normal_from_index(ibase + (uint32_t)j);
    orow[j] = fmaf(expf(lrow[j]), z, mrow[j]);
  }
}

extern "C" void kernel_launch(void* const* d_in, const int* in_sizes, int n_in,
                              void* d_out, int out_size, void* d_ws, size_t ws_size,
                              hipStream_t stream) {
  const float* x  = (const float*)d_in[0];
  const float* mu = (const float*)d_in[1];
  const float* ls = (const float*)d_in[2];
  float* out = (float*)d_out;
  (void)ws_size; (void)in_sizes; (void)n_in; (void)out_size;

  float*  p_ws   = (float*)d_ws;                                   // 64 MiB
  float*  s_part = (float*)((char*)d_ws + (size_t)67108864);       // 64 KiB
  float4* mnT4   = (float4*)((char*)d_ws + (size_t)67174400);      // 64 KiB
  float*  scr    = (float*)((char*)d_ws + (size_t)67239936);       // 1 KiB dummy sink

  prep_mnT<<<1, 64, 0, stream>>>(mu, mnT4);
  dim3 grid(B_, 8);
  xn_cos_softmax<<<grid, 1024, 0, stream>>>(x, mnT4, p_ws, scr);
  dim3 grid2(B_, 4);
  pairwise_sum_n<<<grid2, 256, 0, stream>>>(p_ws, s_part);
  topk_sample<<<B_, 256, 0, stream>>>(s_part, mu, ls, out);
}